// Round 4
// baseline (2466.064 us; speedup 1.0000x reference)
//
#include <hip/hip_runtime.h>
#include <hip/hip_bf16.h>
#include <math.h>

#define B_  64
#define T_  32
#define E_  512
#define D_  512
#define V_  32000
#define NT  31            // T-1 decode steps
#define G4  2048          // 4*D

typedef __attribute__((ext_vector_type(8))) short short8;
typedef __attribute__((ext_vector_type(4))) float f32x4;
typedef __hip_bfloat16 bf16;

__device__ __forceinline__ float sigmoidf_(float x) { return 1.f / (1.f + expf(-x)); }
// gate-interleaved permutation: col n = d*4+gate  <->  original row gate*512+d
__device__ __forceinline__ int perm_(int n) { return ((n & 3) << 9) + (n >> 2); }

// ---------------- kernel 1: stable descending argsort + init ----------------
__global__ void k_sort(const int* __restrict__ caplen, float* __restrict__ out_sind,
                       int* __restrict__ sind, int* __restrict__ declen,
                       int* __restrict__ Mact, int* __restrict__ rowlist,
                       int* __restrict__ rowstart, int* __restrict__ bar,
                       float* __restrict__ hbuf0) {
    __shared__ int s_len[B_];
    __shared__ int s_dl[B_];
    int tid = threadIdx.x;
    if (tid < B_) s_len[tid] = caplen[tid];
    __syncthreads();
    if (tid < B_) {
        int len = s_len[tid];
        int rank = 0;
        for (int j = 0; j < B_; ++j) {
            int lj = s_len[j];
            rank += (lj > len) || (lj == len && j < tid);   // stable: ties by index
        }
        sind[rank] = tid;
        declen[rank] = len - 1;
        s_dl[rank] = len - 1;
        out_sind[rank] = (float)tid;
    }
    __syncthreads();
    if (tid == 0) {
        int base = 0;
        for (int t = 0; t < NT; ++t) {
            rowstart[t] = base;
            int n = 0;
            for (int b = 0; b < B_; ++b) n += (t < s_dl[b]);
            for (int b = 0; b < n; ++b) rowlist[base + b] = t * B_ + b;
            base += n;
        }
        Mact[0] = base;
        bar[0] = 0;
    }
    for (int i = tid; i < B_ * D_; i += blockDim.x) hbuf0[i] = 0.f;
}

// ---------------- kernel 2: zero only inactive prediction rows ----------------
__global__ void k_zero_inact(const int* __restrict__ declen, float4* __restrict__ out) {
    int b = blockIdx.x;           // sorted batch index
    int t = blockIdx.y;
    if (t < declen[b]) return;    // active row -> k_fc writes it
    float4* row = out + (long)(b * NT + t) * (V_ / 4);
    float4 z = make_float4(0.f, 0.f, 0.f, 0.f);
    for (int i = threadIdx.x; i < V_ / 4; i += blockDim.x) row[i] = z;
}

// ---------------- kernel 3: fc_w -> bf16, MFMA-fragment-swizzled ----------------
// dst[id], id = nt*1024 + kci*64 + lane: lane l holds B[col=nt*16+(l&15)][k=kci*32+(l>>4)*8+j]
__global__ void k_cvt_fcw_sw(const float* __restrict__ fcw, short8* __restrict__ dst) {
    int id = blockIdx.x * blockDim.x + threadIdx.x;   // 2,048,000 total
    int lane = id & 63;
    int kci = (id >> 6) & 15;
    int nt = id >> 10;
    int col = (nt << 4) + (lane & 15);
    int k = (kci << 5) + ((lane >> 4) << 3);
    const float* src = fcw + (long)col * D_ + k;
    short8 o;
    #pragma unroll
    for (int j = 0; j < 8; ++j) {
        bf16 v = __float2bfloat16(src[j]);
        o[j] = *(short*)&v;
    }
    dst[id] = o;
}

// ---------------- kernel 4: X = enc_sorted @ Wih[perm].T + bias[perm] (fp32) ----------------
__global__ __launch_bounds__(256) void k_xgemm(
    const float* __restrict__ enc, const float* __restrict__ Wih,
    const float* __restrict__ bih, const float* __restrict__ bhh,
    const int* __restrict__ sind, float* __restrict__ X) {
    __shared__ __align__(16) float sA[16 * 68];
    __shared__ __align__(16) float sB[16 * 68];
    __shared__ int s_sind[B_];
    int tid = threadIdx.x;
    int mt = blockIdx.x;
    int n0 = blockIdx.y * 64;
    if (tid < B_) s_sind[tid] = sind[tid];
    __syncthreads();
    int la = tid >> 2;
    int lk = (tid & 3) << 2;
    int tx = tid & 15, ty = tid >> 4;
    const float* arow = enc + ((long)s_sind[la] * T_ + mt) * E_;
    const float* brow = Wih + (long)perm_(n0 + la) * E_;
    float acc[4][4] = {};
    for (int k0 = 0; k0 < E_; k0 += 16) {
        float4 a4 = *(const float4*)(arow + k0 + lk);
        float4 b4 = *(const float4*)(brow + k0 + lk);
        sA[(lk + 0) * 68 + la] = a4.x; sA[(lk + 1) * 68 + la] = a4.y;
        sA[(lk + 2) * 68 + la] = a4.z; sA[(lk + 3) * 68 + la] = a4.w;
        sB[(lk + 0) * 68 + la] = b4.x; sB[(lk + 1) * 68 + la] = b4.y;
        sB[(lk + 2) * 68 + la] = b4.z; sB[(lk + 3) * 68 + la] = b4.w;
        __syncthreads();
        #pragma unroll
        for (int kk = 0; kk < 16; ++kk) {
            float4 av = *(const float4*)&sA[kk * 68 + (ty << 2)];
            float4 bv = *(const float4*)&sB[kk * 68 + (tx << 2)];
            float a[4] = { av.x, av.y, av.z, av.w };
            float b[4] = { bv.x, bv.y, bv.z, bv.w };
            #pragma unroll
            for (int i = 0; i < 4; ++i)
                #pragma unroll
                for (int j = 0; j < 4; ++j)
                    acc[i][j] = fmaf(a[i], b[j], acc[i][j]);
        }
        __syncthreads();
    }
    #pragma unroll
    for (int i = 0; i < 4; ++i) {
        int b = (ty << 2) + i;
        int row = mt * 64 + b;
        int col0 = n0 + (tx << 2);
        float* xp = X + (long)row * G4 + col0;
        #pragma unroll
        for (int j = 0; j < 4; ++j) {
            int pc = perm_(col0 + j);
            xp[j] = acc[i][j] + bih[pc] + bhh[pc];
        }
    }
}

// ---------------- kernel 5: ALL 31 LSTM steps, persistent + grid barrier ----------------
// 256 blocks x 512 thr. Block bid owns gate-cols [bid*8, bid*8+8) = d's {2bid, 2bid+1}.
// Thread (tx=tid&7, ty=tid>>3): col bid*8+tx, row b=ty. fp32 exact recurrence.
// c and carried-h slice for owned d's live in LDS; h exchanged via global ping-pong.
__global__ __launch_bounds__(512) void k_step_all(
    const float* __restrict__ X, const float* __restrict__ Whh,
    float* __restrict__ hbuf0, float* __restrict__ hbuf1,
    bf16* __restrict__ hstorec, const int* __restrict__ declen,
    const int* __restrict__ rowstart, int* __restrict__ bar) {
    __shared__ float sg[8][65];
    __shared__ float sc[2][64];
    __shared__ float shl[2][64];
    __shared__ int sdl[B_];
    __shared__ int srs[NT];
    int tid = threadIdx.x;
    int bid = blockIdx.x;
    if (tid < B_) {
        sdl[tid] = declen[tid];
        sc[0][tid] = 0.f; sc[1][tid] = 0.f;
        shl[0][tid] = 0.f; shl[1][tid] = 0.f;
    }
    if (tid >= 64 && tid < 64 + NT) srs[tid - 64] = rowstart[tid - 64];
    __syncthreads();
    int tx = tid & 7, ty = tid >> 3;        // ty = 0..63 (= b)
    int n = (bid << 3) + tx;                // global gate-col
    const float* wrow = Whh + (long)perm_(n) * D_;
    int nblocks = gridDim.x;
    for (int t = 0; t < NT; ++t) {
        const float* h = (t & 1) ? hbuf1 : hbuf0;
        float* hnext = (t & 1) ? hbuf0 : hbuf1;
        const float* hrow = h + (ty << 9);
        float a0 = 0.f, a1 = 0.f, a2 = 0.f, a3 = 0.f;
        #pragma unroll 4
        for (int k = 0; k < D_; k += 4) {
            float4 hv = *(const float4*)(hrow + k);
            float4 wv = *(const float4*)(wrow + k);
            a0 = fmaf(hv.x, wv.x, a0);
            a1 = fmaf(hv.y, wv.y, a1);
            a2 = fmaf(hv.z, wv.z, a2);
            a3 = fmaf(hv.w, wv.w, a3);
        }
        float pre = (a0 + a1) + (a2 + a3) + X[((t << 6) + ty) * G4 + n];
        int g = tx & 3;
        sg[tx][ty] = (g == 2) ? tanhf(pre) : sigmoidf_(pre);
        __syncthreads();
        if (tid < 128) {
            int b = tid & 63, dl = tid >> 6;
            float gi = sg[dl * 4 + 0][b];
            float gf = sg[dl * 4 + 1][b];
            float gg = sg[dl * 4 + 2][b];
            float go = sg[dl * 4 + 3][b];
            float co = sc[dl][b];
            float cn = gf * co + gi * gg;
            float hn = go * tanhf(cn);
            int d = (bid << 1) + dl;
            bool act = t < sdl[b];
            if (act) {
                hstorec[(long)(srs[t] + b) * D_ + d] = __float2bfloat16(hn);
                sc[dl][b] = cn;
                shl[dl][b] = hn;
            }
            hnext[(b << 9) + d] = act ? hn : shl[dl][b];
        }
        __syncthreads();
        if (t < NT - 1) {
            // grid barrier: release (wbl2) -> arrive -> spin -> acquire (inv)
            if (tid == 0) {
                __threadfence();
                atomicAdd(bar, 1);
                int target = (t + 1) * nblocks;
                while (__hip_atomic_load(bar, __ATOMIC_RELAXED, __HIP_MEMORY_SCOPE_AGENT) < target)
                    __builtin_amdgcn_s_sleep(2);
                __threadfence();
            }
            __syncthreads();
        }
    }
}

// ---------------- kernel 6: preds = hstorec[0:Ma] @ fcw_sw.T + fc_b (MFMA bf16) ----------------
// A rows compact (0..Ma-1); B pre-swizzled so every fragment load is a coalesced 1KB.
__global__ __launch_bounds__(256) void k_fc(
    const bf16* __restrict__ hstorec, const short8* __restrict__ fcwsw,
    const float* __restrict__ fcb, const int* __restrict__ rowlist,
    const int* __restrict__ Mact, float* __restrict__ out) {
    __shared__ int srow[128];
    int tid = threadIdx.x, lane = tid & 63, w = tid >> 6;
    int mt = blockIdx.x, nb = blockIdx.y;
    int Ma = Mact[0];
    if (mt * 128 >= Ma) return;           // uniform early-exit (inactive rows pre-zeroed)
    if (tid < 128) {
        int r = mt * 128 + tid;
        srow[tid] = (r < Ma) ? rowlist[r] : -1;
    }
    __syncthreads();
    int m0w = (w & 1) * 64;
    int n0w = (w >> 1) * 64;
    int koff = (lane >> 4) << 3;
    const bf16* aptr[4];
    #pragma unroll
    for (int ms = 0; ms < 4; ++ms) {
        int r = mt * 128 + m0w + ms * 16 + (lane & 15);
        if (r >= Ma) r = 0;
        aptr[ms] = hstorec + (long)r * D_ + koff;
    }
    long bbase[4];
    #pragma unroll
    for (int ns = 0; ns < 4; ++ns) {
        int nt = ((nb * 128 + n0w) >> 4) + ns;
        bbase[ns] = (long)nt * 1024 + lane;
    }
    f32x4 acc[4][4] = {};
    #pragma unroll 4
    for (int kci = 0; kci < 16; ++kci) {
        short8 a[4], b[4];
        #pragma unroll
        for (int ms = 0; ms < 4; ++ms) a[ms] = *(const short8*)(aptr[ms] + kci * 32);
        #pragma unroll
        for (int ns = 0; ns < 4; ++ns) b[ns] = fcwsw[bbase[ns] + kci * 64];
        #pragma unroll
        for (int ms = 0; ms < 4; ++ms)
            #pragma unroll
            for (int ns = 0; ns < 4; ++ns)
                acc[ms][ns] = __builtin_amdgcn_mfma_f32_16x16x32_bf16(a[ms], b[ns], acc[ms][ns], 0, 0, 0);
    }
    #pragma unroll
    for (int ms = 0; ms < 4; ++ms) {
        #pragma unroll
        for (int r = 0; r < 4; ++r) {
            int rloc = m0w + ms * 16 + ((lane >> 4) << 2) + r;
            int rv = srow[rloc];
            if (rv < 0) continue;
            int tt = rv >> 6, b = rv & 63;
            #pragma unroll
            for (int ns = 0; ns < 4; ++ns) {
                int n = nb * 128 + n0w + ns * 16 + (lane & 15);
                out[((long)(b * NT + tt)) * V_ + n] = acc[ms][ns][r] + fcb[n];
            }
        }
    }
}

extern "C" void kernel_launch(void* const* d_in, const int* in_sizes, int n_in,
                              void* d_out, int out_size, void* d_ws, size_t ws_size,
                              hipStream_t stream) {
    const float* enc    = (const float*)d_in[0];
    const int*   caplen = (const int*)d_in[1];
    const float* Wih    = (const float*)d_in[2];
    const float* Whh    = (const float*)d_in[3];
    const float* bih    = (const float*)d_in[4];
    const float* bhh    = (const float*)d_in[5];
    const float* fcw    = (const float*)d_in[6];
    const float* fcb    = (const float*)d_in[7];
    float* out = (float*)d_out;

    // workspace carve (~51.5 MB)
    char* ws = (char*)d_ws;
    int* sind     = (int*)ws;                         // 64
    int* declen   = sind + 64;                        // 64
    int* Mact     = declen + 64;                      // 64 (padded)
    int* rowlist  = Mact + 64;                        // 2048
    int* rowstart = rowlist + 2048;                   // 64 (padded)
    int* bar      = rowstart + 64;                    // 64 (padded)
    char* p = (char*)(bar + 64);
    p = (char*)(((size_t)p + 255) & ~(size_t)255);
    float* X       = (float*)p;           p += (size_t)NT * B_ * G4 * 4;   // 16.25 MB
    float* hbuf0   = (float*)p;           p += (size_t)B_ * D_ * 4;        // 128 KB
    float* hbuf1   = (float*)p;           p += (size_t)B_ * D_ * 4;
    bf16*  hstorec = (bf16*)p;            p += (size_t)NT * B_ * D_ * 2;   // 2 MB
    short8* fcwsw  = (short8*)p;          p += (size_t)V_ * D_ * 2;        // 32.8 MB

    float* out_sind = out + (long)B_ * NT * V_;

    k_sort<<<1, 256, 0, stream>>>(caplen, out_sind, sind, declen, Mact, rowlist,
                                  rowstart, bar, hbuf0);
    k_zero_inact<<<dim3(B_, NT), 256, 0, stream>>>(declen, (float4*)out);
    k_cvt_fcw_sw<<<8000, 256, 0, stream>>>(fcw, fcwsw);
    k_xgemm<<<dim3(NT, G4 / 64), 256, 0, stream>>>(enc, Wih, bih, bhh, sind, X);
    k_step_all<<<256, 512, 0, stream>>>(X, Whh, hbuf0, hbuf1, hstorec,
                                        declen, rowstart, bar);
    k_fc<<<dim3(16, V_ / 128), 256, 0, stream>>>(hstorec, fcwsw, fcb, rowlist, Mact, out);
}